// Round 9
// baseline (405.402 us; speedup 1.0000x reference)
//
#include <hip/hip_runtime.h>
#include <hip/hip_bf16.h>
#include <stdint.h>

using u16 = unsigned short;
using u32t = unsigned int;
typedef __bf16 bf16x8 __attribute__((ext_vector_type(8)));
typedef float f32x4 __attribute__((ext_vector_type(4)));
typedef float f32x16 __attribute__((ext_vector_type(16)));

#define SEQ_T 2048
#define DM 1024
#define NH 16
#define HD 64
#define NB 4

__device__ inline u16 f2bfu(float f) {
    __hip_bfloat16 h = __float2bfloat16(f);
    return __builtin_bit_cast(u16, h);
}

__device__ inline bf16x8 ld_frag(const u16* p) {
    return __builtin_bit_cast(bf16x8, *reinterpret_cast<const uint4*>(p));
}

__device__ inline void gload_lds16(const u16* g, u16* l) {
    __builtin_amdgcn_global_load_lds(
        (const __attribute__((address_space(1))) void*)g,
        (__attribute__((address_space(3))) void*)l, 16, 0, 0);
}

// ---------------- convert x (f32 -> bf16), 8 elems/thread ----------------
__global__ __launch_bounds__(256) void cvt_x_kernel(const float* __restrict__ x,
                                                    u16* __restrict__ o) {
    size_t i = (size_t)blockIdx.x * 256 + threadIdx.x;
    const float4* xv = reinterpret_cast<const float4*>(x);
    float4 a = xv[2 * i];
    float4 b = xv[2 * i + 1];
    u16 r[8] = {f2bfu(a.x), f2bfu(a.y), f2bfu(a.z), f2bfu(a.w),
                f2bfu(b.x), f2bfu(b.y), f2bfu(b.z), f2bfu(b.w)};
    *reinterpret_cast<uint4*>(o + i * 8) = *reinterpret_cast<const uint4*>(r);
}

// ---------------- transpose + convert W[K][N] f32 -> Wt[N][K] bf16 ----------------
__global__ __launch_bounds__(256) void trans_w(const float* __restrict__ W,
                                               u16* __restrict__ Wt,
                                               int K, int N) {
    __shared__ __align__(16) float tile[64][72];
    int k0 = blockIdx.y * 64, n0 = blockIdx.x * 64;
    int tid = threadIdx.x;
#pragma unroll
    for (int p = 0; p < 4; ++p) {
        int idx = p * 256 + tid;
        int r = idx >> 4, c = (idx & 15) * 4;
        float4 v = *reinterpret_cast<const float4*>(&W[(size_t)(k0 + r) * N + n0 + c]);
        *reinterpret_cast<float4*>(&tile[r][c]) = v;
    }
    __syncthreads();
#pragma unroll
    for (int p = 0; p < 4; ++p) {
        int idx = p * 256 + tid;
        int nr = idx >> 4, kg = (idx & 15) * 4;
        u16 u[4];
#pragma unroll
        for (int j = 0; j < 4; ++j) u[j] = f2bfu(tile[kg + j][nr]);
        *reinterpret_cast<uint2*>(&Wt[(size_t)(n0 + nr) * K + k0 + kg]) =
            *reinterpret_cast<const uint2*>(u);
    }
}

// ---------------- GEMM: C[M,N] = A[M,K] @ Bt[N,K]^T + bias ----------------
template <int F32OUT>
__global__ __launch_bounds__(256) void gemm_bt(const u16* __restrict__ A,
                                               const u16* __restrict__ Bt,
                                               const float* __restrict__ bias,
                                               float* __restrict__ Cf,
                                               u16* __restrict__ Cb,
                                               int M, int N, int K) {
    __shared__ __align__(16) u16 As[128 * 32];
    __shared__ __align__(16) u16 Bs[128 * 32];
    const int tid = threadIdx.x;
    const int wid = tid >> 6, lane = tid & 63;
    const int lhi = lane >> 4, llo = lane & 15;
    const int m0 = blockIdx.y * 128, n0 = blockIdx.x * 128;
    const int wr = wid >> 1, wc = wid & 1;

    f32x4 acc[4][4];
#pragma unroll
    for (int i = 0; i < 4; ++i)
#pragma unroll
        for (int j = 0; j < 4; ++j) acc[i][j] = (f32x4){0.f, 0.f, 0.f, 0.f};

    for (int k0 = 0; k0 < K; k0 += 32) {
        __syncthreads();
#pragma unroll
        for (int p = 0; p < 2; ++p) {
            int idx = p * 256 + tid;
            int row = idx >> 2, kc = (idx & 3) * 8;
            gload_lds16(A + (size_t)(m0 + row) * K + k0 + kc,
                        As + (size_t)(p * 256 + wid * 64) * 8);
            gload_lds16(Bt + (size_t)(n0 + row) * K + k0 + kc,
                        Bs + (size_t)(p * 256 + wid * 64) * 8);
        }
        __syncthreads();
        bf16x8 af[4], bfr[4];
#pragma unroll
        for (int mt = 0; mt < 4; ++mt)
            af[mt] = ld_frag(&As[(wr * 64 + mt * 16 + llo) * 32 + lhi * 8]);
#pragma unroll
        for (int nt = 0; nt < 4; ++nt)
            bfr[nt] = ld_frag(&Bs[(wc * 64 + nt * 16 + llo) * 32 + lhi * 8]);
#pragma unroll
        for (int mt = 0; mt < 4; ++mt)
#pragma unroll
            for (int nt = 0; nt < 4; ++nt)
                acc[mt][nt] = __builtin_amdgcn_mfma_f32_16x16x32_bf16(
                    af[mt], bfr[nt], acc[mt][nt], 0, 0, 0);
    }

    const int row_base = m0 + wr * 64;
    const int col_base = n0 + wc * 64;
#pragma unroll
    for (int nt = 0; nt < 4; ++nt) {
        int col = col_base + nt * 16 + llo;
        float bv = bias[col];
#pragma unroll
        for (int mt = 0; mt < 4; ++mt) {
#pragma unroll
            for (int r = 0; r < 4; ++r) {
                int row = row_base + mt * 16 + lhi * 4 + r;
                float v = acc[mt][nt][r] + bv;
                if (F32OUT)
                    Cf[(size_t)row * N + col] = v;
                else
                    Cb[(size_t)row * N + col] = f2bfu(v);
            }
        }
    }
}

// ---------------- causal flash attention, swapped-operand 32x32 MFMA ----------------
// Block: 256 thr (4 waves), wave owns 32 q rows -> block = 128 q rows.
// Grid: 1024 = 16 q-chunks x 64 (b,h), longest chunks first; 4 blocks/CU resident.
// S^T = mfma(K, Q); in-register softmax (kv register-local, 1 shfl_xor(32));
// defer-max (THR=8, log2 units); P via cvt_pk_bf16 + permlane32_swap;
// O^T += mfma(V^T, P^T). K staged via global_load_lds (swizzled source);
// V transposed into LDS with chunk-XOR swizzle. Single barrier/tile, prefetch ahead.
__global__ __launch_bounds__(256, 4) void attn_kernel(const u16* __restrict__ qkv,
                                                      u16* __restrict__ o) {
    __shared__ __align__(16) u16 smem[17408];  // K: 2x4096 u16 @0, Vt: 2x4608 u16 @8192
    const int bid = blockIdx.x;
    const int qc = 15 - (bid >> 6);            // longest-first
    const int bh = bid & 63;
    const int b = bh >> 4, h = bh & 15;
    const int tid = threadIdx.x;
    const int wid = tid >> 6, lane = tid & 63;
    const int l31 = lane & 31, lh = lane >> 5;
    const u16* base = qkv + (size_t)b * SEQ_T * (3 * DM);
    const int qrow0 = qc * 128 + wid * 32;
    const int q_abs = qrow0 + l31;
    const int nkv = 2 * qc + 2;

    // Q B-fragments: lane l31 = q, k(d) = km*16 + lh*8 + e  (natural row read)
    bf16x8 qf[4];
    {
        const u16* qp = base + (size_t)q_abs * (3 * DM) + h * HD + lh * 8;
#pragma unroll
        for (int km = 0; km < 4; ++km) qf[km] = ld_frag(qp + km * 16);
    }

    f32x16 oac0, oac1;  // O^T accs: lane l31 = q, d via (reg,lh)
#pragma unroll
    for (int r = 0; r < 16; ++r) { oac0[r] = 0.f; oac1[r] = 0.f; }
    float m_run = -1e30f, l_run = 0.f;

    uint4 va, vb;
    const int vpr = tid >> 3, vm = tid & 7;

    auto stageK = [&](int kb, int bi) {
#pragma unroll
        for (int p = 0; p < 2; ++p) {
            int kv = p * 32 + wid * 8 + (lane >> 3);
            int cl = lane & 7;
            const u16* src = base + (size_t)(kb * 64 + kv) * (3 * DM) + DM + h * HD +
                             ((cl ^ (kv & 7)) * 8);
            gload_lds16(src, smem + bi * 4096 + p * 2048 + wid * 512);
        }
    };
    auto loadV = [&](int kb) {
        const u16* vp =
            base + (size_t)(kb * 64 + 2 * vpr) * (3 * DM) + 2 * DM + h * HD + vm * 8;
        va = *reinterpret_cast<const uint4*>(vp);
        vb = *reinterpret_cast<const uint4*>(vp + 3 * DM);
    };
    auto writeV = [&](int bi) {  // Vt[d][kv], rows 72 u16, chunk-XOR swizzled
        u16 ua[8], ub[8];
        *reinterpret_cast<uint4*>(ua) = va;
        *reinterpret_cast<uint4*>(ub) = vb;
        const int cb = vpr >> 2, off = 2 * (vpr & 3);
        const int sw = (2 * vm) & 7;  // (2*(d>>3))&7, d>>3 == vm
        u16* vt = smem + 8192 + bi * 4608;
#pragma unroll
        for (int j = 0; j < 8; ++j) {
            int d = vm * 8 + j;
            u32t val = (u32t)ua[j] | ((u32t)ub[j] << 16);
            *reinterpret_cast<u32t*>(vt + d * 72 + ((cb ^ sw) * 8) + off) = val;
        }
    };

    stageK(0, 0);
    loadV(0);
    writeV(0);
    __syncthreads();

    const int vsw = (2 * (l31 >> 3)) & 7;
    const int qmax = qrow0 + 31;
    const float SC2 = 0.18033688f;  // (1/sqrt(64)) * log2(e); softmax in base-2

    for (int kb = 0; kb < nkv; ++kb) {
        const int cur = kb & 1;
        const bool pre = (kb + 1 < nkv);
        if (pre) { stageK(kb + 1, cur ^ 1); loadV(kb + 1); }

        if (kb * 64 <= qmax) {
            // ---- S^T = K · Q^T ----
            f32x16 s0, s1;
#pragma unroll
            for (int r = 0; r < 16; ++r) { s0[r] = 0.f; s1[r] = 0.f; }
            const u16* kbase = smem + cur * 4096;
            __builtin_amdgcn_s_setprio(1);
#pragma unroll
            for (int km = 0; km < 4; ++km) {
                bf16x8 kf = ld_frag(kbase + l31 * 64 + (((km * 2 + lh) ^ (l31 & 7)) * 8));
                s0 = __builtin_amdgcn_mfma_f32_32x32x16_bf16(kf, qf[km], s0, 0, 0, 0);
            }
#pragma unroll
            for (int km = 0; km < 4; ++km) {
                bf16x8 kf = ld_frag(kbase + (32 + l31) * 64 + (((km * 2 + lh) ^ (l31 & 7)) * 8));
                s1 = __builtin_amdgcn_mfma_f32_32x32x16_bf16(kf, qf[km], s1, 0, 0, 0);
            }
            __builtin_amdgcn_s_setprio(0);

            // ---- scale + causal mask ----
            if (kb * 64 + 63 > qrow0) {
#pragma unroll
                for (int r = 0; r < 16; ++r) {
                    int ka = kb * 64 + (r & 3) + 8 * (r >> 2) + 4 * lh;
                    s0[r] = (ka > q_abs) ? -1e30f : s0[r] * SC2;
                    s1[r] = (ka + 32 > q_abs) ? -1e30f : s1[r] * SC2;
                }
            } else {
#pragma unroll
                for (int r = 0; r < 16; ++r) { s0[r] *= SC2; s1[r] *= SC2; }
            }

            // ---- online softmax with defer-max (kv register-local) ----
            float pm = s0[0];
#pragma unroll
            for (int r = 1; r < 16; ++r) pm = fmaxf(pm, s0[r]);
#pragma unroll
            for (int r = 0; r < 16; ++r) pm = fmaxf(pm, s1[r]);
            pm = fmaxf(pm, __shfl_xor(pm, 32));
            if (!__all(pm - m_run <= 8.f)) {
                const float mnew = fmaxf(m_run, pm);
                const float sc = exp2f(m_run - mnew);
                m_run = mnew;
                l_run *= sc;
#pragma unroll
                for (int r = 0; r < 16; ++r) { oac0[r] *= sc; oac1[r] *= sc; }
            }
            float sum = 0.f;
#pragma unroll
            for (int r = 0; r < 16; ++r) { float p = exp2f(s0[r] - m_run); s0[r] = p; sum += p; }
#pragma unroll
            for (int r = 0; r < 16; ++r) { float p = exp2f(s1[r] - m_run); s1[r] = p; sum += p; }
            sum += __shfl_xor(sum, 32);
            l_run += sum;

            // ---- P -> bf16 B-fragments: cvt_pk + permlane32_swap ----
            u32t pk0[8], pk1[8];
#pragma unroll
            for (int w = 0; w < 8; ++w) {
                float a0 = s0[2 * w], b0 = s0[2 * w + 1];
                float a1 = s1[2 * w], b1 = s1[2 * w + 1];
                asm("v_cvt_pk_bf16_f32 %0, %1, %2" : "=v"(pk0[w]) : "v"(a0), "v"(b0));
                asm("v_cvt_pk_bf16_f32 %0, %1, %2" : "=v"(pk1[w]) : "v"(a1), "v"(b1));
            }
            asm("v_permlane32_swap_b32 %0, %1" : "+v"(pk0[0]), "+v"(pk0[2]));
            asm("v_permlane32_swap_b32 %0, %1" : "+v"(pk0[1]), "+v"(pk0[3]));
            asm("v_permlane32_swap_b32 %0, %1" : "+v"(pk0[4]), "+v"(pk0[6]));
            asm("v_permlane32_swap_b32 %0, %1" : "+v"(pk0[5]), "+v"(pk0[7]));
            asm("v_permlane32_swap_b32 %0, %1" : "+v"(pk1[0]), "+v"(pk1[2]));
            asm("v_permlane32_swap_b32 %0, %1" : "+v"(pk1[1]), "+v"(pk1[3]));
            asm("v_permlane32_swap_b32 %0, %1" : "+v"(pk1[4]), "+v"(pk1[6]));
            asm("v_permlane32_swap_b32 %0, %1" : "+v"(pk1[5]), "+v"(pk1[7]));
            bf16x8 pf[4];
            {
                uint4 t0 = {pk0[0], pk0[1], pk0[2], pk0[3]};
                uint4 t1 = {pk0[4], pk0[5], pk0[6], pk0[7]};
                uint4 t2 = {pk1[0], pk1[1], pk1[2], pk1[3]};
                uint4 t3 = {pk1[4], pk1[5], pk1[6], pk1[7]};
                pf[0] = __builtin_bit_cast(bf16x8, t0);
                pf[1] = __builtin_bit_cast(bf16x8, t1);
                pf[2] = __builtin_bit_cast(bf16x8, t2);
                pf[3] = __builtin_bit_cast(bf16x8, t3);
            }

            // ---- O^T += V^T · P^T ----
            const u16* vbase = smem + 8192 + cur * 4608;
            __builtin_amdgcn_s_setprio(1);
#pragma unroll
            for (int km = 0; km < 4; ++km) {
                bf16x8 vf = ld_frag(vbase + l31 * 72 + (((km * 2 + lh) ^ vsw) * 8));
                oac0 = __builtin_amdgcn_mfma_f32_32x32x16_bf16(vf, pf[km], oac0, 0, 0, 0);
            }
#pragma unroll
            for (int km = 0; km < 4; ++km) {
                bf16x8 vf = ld_frag(vbase + (32 + l31) * 72 + (((km * 2 + lh) ^ vsw) * 8));
                oac1 = __builtin_amdgcn_mfma_f32_32x32x16_bf16(vf, pf[km], oac1, 0, 0, 0);
            }
            __builtin_amdgcn_s_setprio(0);
        }

        if (pre) writeV(cur ^ 1);
        __syncthreads();
    }

    // ---- epilogue: normalize, transpose O^T->O via LDS, coalesced store ----
    const float inv = 1.f / l_run;
    u16* osh = smem + wid * 2240;  // per-wave [32 q][70 u16]
#pragma unroll
    for (int r = 0; r < 16; ++r) {
        int dl = (r & 3) + 8 * (r >> 2) + 4 * lh;
        osh[l31 * 70 + dl] = f2bfu(oac0[r] * inv);
        osh[l31 * 70 + 32 + dl] = f2bfu(oac1[r] * inv);
    }
    __syncthreads();
    {
        // lane (l31, lh) writes q = l31, d = lh*32 + 0..31  (full 64-d coverage)
        const u16* rs = osh + l31 * 70 + lh * 32;
        u16* op = o + (size_t)(b * SEQ_T + qrow0 + l31) * DM + h * HD + lh * 32;
        u32t w[16];
#pragma unroll
        for (int i = 0; i < 16; ++i) w[i] = *reinterpret_cast<const u32t*>(rs + i * 2);
#pragma unroll
        for (int i = 0; i < 4; ++i) {
            uint4 t = {w[4 * i], w[4 * i + 1], w[4 * i + 2], w[4 * i + 3]};
            *reinterpret_cast<uint4*>(op + 8 * i) = t;
        }
    }
}

extern "C" void kernel_launch(void* const* d_in, const int* in_sizes, int n_in,
                              void* d_out, int out_size, void* d_ws, size_t ws_size,
                              hipStream_t stream) {
    const float* x = (const float*)d_in[0];
    const float* Wqkv = (const float*)d_in[1];
    const float* bqkv = (const float*)d_in[2];
    const float* Wproj = (const float*)d_in[3];
    const float* bproj = (const float*)d_in[4];
    float* out = (float*)d_out;
    char* ws = (char*)d_ws;

    u16* xb   = (u16*)(ws);                         // 16,777,216 B
    u16* wtq  = (u16*)(ws + 16777216);              //  6,291,456 B
    u16* wtp  = (u16*)(ws + 23068672);              //  2,097,152 B
    u16* qkvb = (u16*)(ws + 25165824);              // 50,331,648 B
    u16* ob   = (u16*)(ws + 75497472);              // 16,777,216 B

    cvt_x_kernel<<<4096, 256, 0, stream>>>(x, xb);
    trans_w<<<dim3(3072 / 64, 1024 / 64), 256, 0, stream>>>(Wqkv, wtq, 1024, 3072);
    trans_w<<<dim3(1024 / 64, 1024 / 64), 256, 0, stream>>>(Wproj, wtp, 1024, 1024);

    gemm_bt<0><<<dim3(3072 / 128, 8192 / 128), 256, 0, stream>>>(
        xb, wtq, bqkv, nullptr, qkvb, 8192, 3072, 1024);

    attn_kernel<<<1024, 256, 0, stream>>>(qkvb, ob);

    gemm_bt<1><<<dim3(1024 / 128, 8192 / 128), 256, 0, stream>>>(
        ob, wtp, bproj, out, nullptr, 8192, 1024, 1024);
}

// Round 10
// 297.880 us; speedup vs baseline: 1.3610x; 1.3610x over previous
//
#include <hip/hip_runtime.h>
#include <hip/hip_bf16.h>
#include <stdint.h>

using u16 = unsigned short;
using u32t = unsigned int;
typedef __bf16 bf16x8 __attribute__((ext_vector_type(8)));
typedef float f32x4 __attribute__((ext_vector_type(4)));
typedef float f32x16 __attribute__((ext_vector_type(16)));

#define SEQ_T 2048
#define DM 1024
#define NH 16
#define HD 64
#define NB 4

__device__ inline u16 f2bfu(float f) {
    __hip_bfloat16 h = __float2bfloat16(f);
    return __builtin_bit_cast(u16, h);
}

__device__ inline bf16x8 ld_frag(const u16* p) {
    return __builtin_bit_cast(bf16x8, *reinterpret_cast<const uint4*>(p));
}

__device__ inline void gload_lds16(const u16* g, u16* l) {
    __builtin_amdgcn_global_load_lds(
        (const __attribute__((address_space(1))) void*)g,
        (__attribute__((address_space(3))) void*)l, 16, 0, 0);
}

// ---------------- convert x (f32 -> bf16), 8 elems/thread ----------------
__global__ __launch_bounds__(256) void cvt_x_kernel(const float* __restrict__ x,
                                                    u16* __restrict__ o) {
    size_t i = (size_t)blockIdx.x * 256 + threadIdx.x;
    const float4* xv = reinterpret_cast<const float4*>(x);
    float4 a = xv[2 * i];
    float4 b = xv[2 * i + 1];
    u16 r[8] = {f2bfu(a.x), f2bfu(a.y), f2bfu(a.z), f2bfu(a.w),
                f2bfu(b.x), f2bfu(b.y), f2bfu(b.z), f2bfu(b.w)};
    *reinterpret_cast<uint4*>(o + i * 8) = *reinterpret_cast<const uint4*>(r);
}

// ---------------- transpose + convert W[K][N] f32 -> Wt[N][K] bf16 ----------------
__global__ __launch_bounds__(256) void trans_w(const float* __restrict__ W,
                                               u16* __restrict__ Wt,
                                               int K, int N) {
    __shared__ __align__(16) float tile[64][72];
    int k0 = blockIdx.y * 64, n0 = blockIdx.x * 64;
    int tid = threadIdx.x;
#pragma unroll
    for (int p = 0; p < 4; ++p) {
        int idx = p * 256 + tid;
        int r = idx >> 4, c = (idx & 15) * 4;
        float4 v = *reinterpret_cast<const float4*>(&W[(size_t)(k0 + r) * N + n0 + c]);
        *reinterpret_cast<float4*>(&tile[r][c]) = v;
    }
    __syncthreads();
#pragma unroll
    for (int p = 0; p < 4; ++p) {
        int idx = p * 256 + tid;
        int nr = idx >> 4, kg = (idx & 15) * 4;
        u16 u[4];
#pragma unroll
        for (int j = 0; j < 4; ++j) u[j] = f2bfu(tile[kg + j][nr]);
        *reinterpret_cast<uint2*>(&Wt[(size_t)(n0 + nr) * K + k0 + kg]) =
            *reinterpret_cast<const uint2*>(u);
    }
}

// ---------------- GEMM: C[M,N] = A[M,K] @ Bt[N,K]^T + bias ----------------
template <int F32OUT>
__global__ __launch_bounds__(256) void gemm_bt(const u16* __restrict__ A,
                                               const u16* __restrict__ Bt,
                                               const float* __restrict__ bias,
                                               float* __restrict__ Cf,
                                               u16* __restrict__ Cb,
                                               int M, int N, int K) {
    __shared__ __align__(16) u16 As[128 * 32];
    __shared__ __align__(16) u16 Bs[128 * 32];
    const int tid = threadIdx.x;
    const int wid = tid >> 6, lane = tid & 63;
    const int lhi = lane >> 4, llo = lane & 15;
    const int m0 = blockIdx.y * 128, n0 = blockIdx.x * 128;
    const int wr = wid >> 1, wc = wid & 1;

    f32x4 acc[4][4];
#pragma unroll
    for (int i = 0; i < 4; ++i)
#pragma unroll
        for (int j = 0; j < 4; ++j) acc[i][j] = (f32x4){0.f, 0.f, 0.f, 0.f};

    for (int k0 = 0; k0 < K; k0 += 32) {
        __syncthreads();
#pragma unroll
        for (int p = 0; p < 2; ++p) {
            int idx = p * 256 + tid;
            int row = idx >> 2, kc = (idx & 3) * 8;
            gload_lds16(A + (size_t)(m0 + row) * K + k0 + kc,
                        As + (size_t)(p * 256 + wid * 64) * 8);
            gload_lds16(Bt + (size_t)(n0 + row) * K + k0 + kc,
                        Bs + (size_t)(p * 256 + wid * 64) * 8);
        }
        __syncthreads();
        bf16x8 af[4], bfr[4];
#pragma unroll
        for (int mt = 0; mt < 4; ++mt)
            af[mt] = ld_frag(&As[(wr * 64 + mt * 16 + llo) * 32 + lhi * 8]);
#pragma unroll
        for (int nt = 0; nt < 4; ++nt)
            bfr[nt] = ld_frag(&Bs[(wc * 64 + nt * 16 + llo) * 32 + lhi * 8]);
#pragma unroll
        for (int mt = 0; mt < 4; ++mt)
#pragma unroll
            for (int nt = 0; nt < 4; ++nt)
                acc[mt][nt] = __builtin_amdgcn_mfma_f32_16x16x32_bf16(
                    af[mt], bfr[nt], acc[mt][nt], 0, 0, 0);
    }

    const int row_base = m0 + wr * 64;
    const int col_base = n0 + wc * 64;
#pragma unroll
    for (int nt = 0; nt < 4; ++nt) {
        int col = col_base + nt * 16 + llo;
        float bv = bias[col];
#pragma unroll
        for (int mt = 0; mt < 4; ++mt) {
#pragma unroll
            for (int r = 0; r < 4; ++r) {
                int row = row_base + mt * 16 + lhi * 4 + r;
                float v = acc[mt][nt][r] + bv;
                if (F32OUT)
                    Cf[(size_t)row * N + col] = v;
                else
                    Cb[(size_t)row * N + col] = f2bfu(v);
            }
        }
    }
}

// ---------------- causal flash attention, swapped-operand 32x32 MFMA ----------------
// Block: 256 thr (4 waves), wave owns 32 q rows -> block = 128 q rows.
// Grid: 1024 = 16 q-chunks x 64 (b,h); qc chosen via balance permutation so each
// CU's 4 resident blocks sum to 68 tiles (round-robin bid->CU assumed).
// S^T = mfma(K, Q); in-register softmax (kv register-local, 1 shfl_xor(32));
// defer-max (THR=8, log2 units); P via cvt_pk_bf16 + permlane32_swap;
// O^T += mfma(V^T, P^T). K staged via global_load_lds (swizzled source);
// V transposed into LDS with chunk-XOR swizzle. Single barrier/tile, prefetch ahead.
__global__ __launch_bounds__(256, 3) void attn_kernel(const u16* __restrict__ qkv,
                                                      u16* __restrict__ o) {
    __shared__ __align__(16) u16 smem[17408];  // K: 2x4096 u16 @0, Vt: 2x4608 u16 @8192
    const int bid = blockIdx.x;
    // CU-balance permutation: residency classes {g,g+4,g+8,g+12} each sum qc = 30.
    const int qcmap[16] = {15, 14, 13, 12, 8, 9, 10, 11, 4, 5, 6, 7, 3, 2, 1, 0};
    const int qc = qcmap[bid >> 6];
    const int bh = bid & 63;
    const int b = bh >> 4, h = bh & 15;
    const int tid = threadIdx.x;
    const int wid = tid >> 6, lane = tid & 63;
    const int l31 = lane & 31, lh = lane >> 5;
    const u16* base = qkv + (size_t)b * SEQ_T * (3 * DM);
    const int qrow0 = qc * 128 + wid * 32;
    const int q_abs = qrow0 + l31;
    const int nkv = 2 * qc + 2;

    // Q B-fragments: lane l31 = q, k(d) = km*16 + lh*8 + e  (natural row read)
    bf16x8 qf[4];
    {
        const u16* qp = base + (size_t)q_abs * (3 * DM) + h * HD + lh * 8;
#pragma unroll
        for (int km = 0; km < 4; ++km) qf[km] = ld_frag(qp + km * 16);
    }

    f32x16 oac0, oac1;  // O^T accs: lane l31 = q, d via (reg,lh)
#pragma unroll
    for (int r = 0; r < 16; ++r) { oac0[r] = 0.f; oac1[r] = 0.f; }
    float m_run = -1e30f, l_run = 0.f;

    uint4 va, vb;
    const int vpr = tid >> 3, vm = tid & 7;

    auto stageK = [&](int kb, int bi) {
#pragma unroll
        for (int p = 0; p < 2; ++p) {
            int kv = p * 32 + wid * 8 + (lane >> 3);
            int cl = lane & 7;
            const u16* src = base + (size_t)(kb * 64 + kv) * (3 * DM) + DM + h * HD +
                             ((cl ^ (kv & 7)) * 8);
            gload_lds16(src, smem + bi * 4096 + p * 2048 + wid * 512);
        }
    };
    auto loadV = [&](int kb) {
        const u16* vp =
            base + (size_t)(kb * 64 + 2 * vpr) * (3 * DM) + 2 * DM + h * HD + vm * 8;
        va = *reinterpret_cast<const uint4*>(vp);
        vb = *reinterpret_cast<const uint4*>(vp + 3 * DM);
    };
    auto writeV = [&](int bi) {  // Vt[d][kv], rows 72 u16, chunk-XOR swizzled
        u16 ua[8], ub[8];
        *reinterpret_cast<uint4*>(ua) = va;
        *reinterpret_cast<uint4*>(ub) = vb;
        const int cb = vpr >> 2, off = 2 * (vpr & 3);
        const int sw = (2 * vm) & 7;  // (2*(d>>3))&7, d>>3 == vm
        u16* vt = smem + 8192 + bi * 4608;
#pragma unroll
        for (int j = 0; j < 8; ++j) {
            int d = vm * 8 + j;
            u32t val = (u32t)ua[j] | ((u32t)ub[j] << 16);
            *reinterpret_cast<u32t*>(vt + d * 72 + ((cb ^ sw) * 8) + off) = val;
        }
    };

    stageK(0, 0);
    loadV(0);
    writeV(0);
    __syncthreads();

    const int vsw = (2 * (l31 >> 3)) & 7;
    const int qmax = qrow0 + 31;
    const float SC2 = 0.18033688f;  // (1/sqrt(64)) * log2(e); softmax in base-2

    for (int kb = 0; kb < nkv; ++kb) {
        const int cur = kb & 1;
        const bool pre = (kb + 1 < nkv);
        if (pre) { stageK(kb + 1, cur ^ 1); loadV(kb + 1); }

        if (kb * 64 <= qmax) {
            // ---- S^T = K · Q^T ----
            f32x16 s0, s1;
#pragma unroll
            for (int r = 0; r < 16; ++r) { s0[r] = 0.f; s1[r] = 0.f; }
            const u16* kbase = smem + cur * 4096;
            __builtin_amdgcn_s_setprio(1);
#pragma unroll
            for (int km = 0; km < 4; ++km) {
                bf16x8 kf = ld_frag(kbase + l31 * 64 + (((km * 2 + lh) ^ (l31 & 7)) * 8));
                s0 = __builtin_amdgcn_mfma_f32_32x32x16_bf16(kf, qf[km], s0, 0, 0, 0);
            }
#pragma unroll
            for (int km = 0; km < 4; ++km) {
                bf16x8 kf = ld_frag(kbase + (32 + l31) * 64 + (((km * 2 + lh) ^ (l31 & 7)) * 8));
                s1 = __builtin_amdgcn_mfma_f32_32x32x16_bf16(kf, qf[km], s1, 0, 0, 0);
            }
            __builtin_amdgcn_s_setprio(0);

            // ---- scale + causal mask ----
            if (kb * 64 + 63 > qrow0) {
#pragma unroll
                for (int r = 0; r < 16; ++r) {
                    int ka = kb * 64 + (r & 3) + 8 * (r >> 2) + 4 * lh;
                    s0[r] = (ka > q_abs) ? -1e30f : s0[r] * SC2;
                    s1[r] = (ka + 32 > q_abs) ? -1e30f : s1[r] * SC2;
                }
            } else {
#pragma unroll
                for (int r = 0; r < 16; ++r) { s0[r] *= SC2; s1[r] *= SC2; }
            }

            // ---- online softmax with defer-max (kv register-local) ----
            float pm = s0[0];
#pragma unroll
            for (int r = 1; r < 16; ++r) pm = fmaxf(pm, s0[r]);
#pragma unroll
            for (int r = 0; r < 16; ++r) pm = fmaxf(pm, s1[r]);
            pm = fmaxf(pm, __shfl_xor(pm, 32));
            if (!__all(pm - m_run <= 8.f)) {
                const float mnew = fmaxf(m_run, pm);
                const float sc = exp2f(m_run - mnew);
                m_run = mnew;
                l_run *= sc;
#pragma unroll
                for (int r = 0; r < 16; ++r) { oac0[r] *= sc; oac1[r] *= sc; }
            }
            float sum = 0.f;
#pragma unroll
            for (int r = 0; r < 16; ++r) { float p = exp2f(s0[r] - m_run); s0[r] = p; sum += p; }
#pragma unroll
            for (int r = 0; r < 16; ++r) { float p = exp2f(s1[r] - m_run); s1[r] = p; sum += p; }
            sum += __shfl_xor(sum, 32);
            l_run += sum;

            // ---- P -> bf16 B-fragments: cvt_pk + permlane32_swap ----
            u32t pk0[8], pk1[8];
#pragma unroll
            for (int w = 0; w < 8; ++w) {
                float a0 = s0[2 * w], b0 = s0[2 * w + 1];
                float a1 = s1[2 * w], b1 = s1[2 * w + 1];
                asm("v_cvt_pk_bf16_f32 %0, %1, %2" : "=v"(pk0[w]) : "v"(a0), "v"(b0));
                asm("v_cvt_pk_bf16_f32 %0, %1, %2" : "=v"(pk1[w]) : "v"(a1), "v"(b1));
            }
            asm("v_permlane32_swap_b32 %0, %1" : "+v"(pk0[0]), "+v"(pk0[2]));
            asm("v_permlane32_swap_b32 %0, %1" : "+v"(pk0[1]), "+v"(pk0[3]));
            asm("v_permlane32_swap_b32 %0, %1" : "+v"(pk0[4]), "+v"(pk0[6]));
            asm("v_permlane32_swap_b32 %0, %1" : "+v"(pk0[5]), "+v"(pk0[7]));
            asm("v_permlane32_swap_b32 %0, %1" : "+v"(pk1[0]), "+v"(pk1[2]));
            asm("v_permlane32_swap_b32 %0, %1" : "+v"(pk1[1]), "+v"(pk1[3]));
            asm("v_permlane32_swap_b32 %0, %1" : "+v"(pk1[4]), "+v"(pk1[6]));
            asm("v_permlane32_swap_b32 %0, %1" : "+v"(pk1[5]), "+v"(pk1[7]));
            bf16x8 pf[4];
            {
                uint4 t0 = {pk0[0], pk0[1], pk0[2], pk0[3]};
                uint4 t1 = {pk0[4], pk0[5], pk0[6], pk0[7]};
                uint4 t2 = {pk1[0], pk1[1], pk1[2], pk1[3]};
                uint4 t3 = {pk1[4], pk1[5], pk1[6], pk1[7]};
                pf[0] = __builtin_bit_cast(bf16x8, t0);
                pf[1] = __builtin_bit_cast(bf16x8, t1);
                pf[2] = __builtin_bit_cast(bf16x8, t2);
                pf[3] = __builtin_bit_cast(bf16x8, t3);
            }

            // ---- O^T += V^T · P^T ----
            const u16* vbase = smem + 8192 + cur * 4608;
            __builtin_amdgcn_s_setprio(1);
#pragma unroll
            for (int km = 0; km < 4; ++km) {
                bf16x8 vf = ld_frag(vbase + l31 * 72 + (((km * 2 + lh) ^ vsw) * 8));
                oac0 = __builtin_amdgcn_mfma_f32_32x32x16_bf16(vf, pf[km], oac0, 0, 0, 0);
            }
#pragma unroll
            for (int km = 0; km < 4; ++km) {
                bf16x8 vf = ld_frag(vbase + (32 + l31) * 72 + (((km * 2 + lh) ^ vsw) * 8));
                oac1 = __builtin_amdgcn_mfma_f32_32x32x16_bf16(vf, pf[km], oac1, 0, 0, 0);
            }
            __builtin_amdgcn_s_setprio(0);
        }

        if (pre) writeV(cur ^ 1);
        __syncthreads();
    }

    // ---- epilogue: normalize, transpose O^T->O via LDS, coalesced store ----
    const float inv = 1.f / l_run;
    u16* osh = smem + wid * 2240;  // per-wave [32 q][70 u16]
#pragma unroll
    for (int r = 0; r < 16; ++r) {
        int dl = (r & 3) + 8 * (r >> 2) + 4 * lh;
        osh[l31 * 70 + dl] = f2bfu(oac0[r] * inv);
        osh[l31 * 70 + 32 + dl] = f2bfu(oac1[r] * inv);
    }
    __syncthreads();
    {
        // lane (l31, lh) writes q = l31, d = lh*32 + 0..31  (full 64-d coverage)
        const u16* rs = osh + l31 * 70 + lh * 32;
        u16* op = o + (size_t)(b * SEQ_T + qrow0 + l31) * DM + h * HD + lh * 32;
        u32t w[16];
#pragma unroll
        for (int i = 0; i < 16; ++i) w[i] = *reinterpret_cast<const u32t*>(rs + i * 2);
#pragma unroll
        for (int i = 0; i < 4; ++i) {
            uint4 t = {w[4 * i], w[4 * i + 1], w[4 * i + 2], w[4 * i + 3]};
            *reinterpret_cast<uint4*>(op + 8 * i) = t;
        }
    }
}

extern "C" void kernel_launch(void* const* d_in, const int* in_sizes, int n_in,
                              void* d_out, int out_size, void* d_ws, size_t ws_size,
                              hipStream_t stream) {
    const float* x = (const float*)d_in[0];
    const float* Wqkv = (const float*)d_in[1];
    const float* bqkv = (const float*)d_in[2];
    const float* Wproj = (const float*)d_in[3];
    const float* bproj = (const float*)d_in[4];
    float* out = (float*)d_out;
    char* ws = (char*)d_ws;

    u16* xb   = (u16*)(ws);                         // 16,777,216 B
    u16* wtq  = (u16*)(ws + 16777216);              //  6,291,456 B
    u16* wtp  = (u16*)(ws + 23068672);              //  2,097,152 B
    u16* qkvb = (u16*)(ws + 25165824);              // 50,331,648 B
    u16* ob   = (u16*)(ws + 75497472);              // 16,777,216 B

    cvt_x_kernel<<<4096, 256, 0, stream>>>(x, xb);
    trans_w<<<dim3(3072 / 64, 1024 / 64), 256, 0, stream>>>(Wqkv, wtq, 1024, 3072);
    trans_w<<<dim3(1024 / 64, 1024 / 64), 256, 0, stream>>>(Wproj, wtp, 1024, 1024);

    gemm_bt<0><<<dim3(3072 / 128, 8192 / 128), 256, 0, stream>>>(
        xb, wtq, bqkv, nullptr, qkvb, 8192, 3072, 1024);

    attn_kernel<<<1024, 256, 0, stream>>>(qkvb, ob);

    gemm_bt<1><<<dim3(1024 / 128, 8192 / 128), 256, 0, stream>>>(
        ob, wtp, bproj, out, nullptr, 8192, 1024, 1024);
}

// Round 11
// 297.800 us; speedup vs baseline: 1.3613x; 1.0003x over previous
//
#include <hip/hip_runtime.h>
#include <hip/hip_bf16.h>
#include <stdint.h>

using u16 = unsigned short;
using u32t = unsigned int;
typedef __bf16 bf16x8 __attribute__((ext_vector_type(8)));
typedef float f32x4 __attribute__((ext_vector_type(4)));
typedef float f32x16 __attribute__((ext_vector_type(16)));

#define SEQ_T 2048
#define DM 1024
#define NH 16
#define HD 64
#define NB 4

__device__ inline u16 f2bfu(float f) {
    __hip_bfloat16 h = __float2bfloat16(f);
    return __builtin_bit_cast(u16, h);
}

__device__ inline bf16x8 ld_frag(const u16* p) {
    return __builtin_bit_cast(bf16x8, *reinterpret_cast<const uint4*>(p));
}

__device__ inline void gload_lds16(const u16* g, u16* l) {
    __builtin_amdgcn_global_load_lds(
        (const __attribute__((address_space(1))) void*)g,
        (__attribute__((address_space(3))) void*)l, 16, 0, 0);
}

// ---------------- convert x (f32 -> bf16), 8 elems/thread ----------------
__global__ __launch_bounds__(256) void cvt_x_kernel(const float* __restrict__ x,
                                                    u16* __restrict__ o) {
    size_t i = (size_t)blockIdx.x * 256 + threadIdx.x;
    const float4* xv = reinterpret_cast<const float4*>(x);
    float4 a = xv[2 * i];
    float4 b = xv[2 * i + 1];
    u16 r[8] = {f2bfu(a.x), f2bfu(a.y), f2bfu(a.z), f2bfu(a.w),
                f2bfu(b.x), f2bfu(b.y), f2bfu(b.z), f2bfu(b.w)};
    *reinterpret_cast<uint4*>(o + i * 8) = *reinterpret_cast<const uint4*>(r);
}

// ---------------- transpose + convert W[K][N] f32 -> Wt[N][K] bf16 ----------------
__global__ __launch_bounds__(256) void trans_w(const float* __restrict__ W,
                                               u16* __restrict__ Wt,
                                               int K, int N) {
    __shared__ __align__(16) float tile[64][72];
    int k0 = blockIdx.y * 64, n0 = blockIdx.x * 64;
    int tid = threadIdx.x;
#pragma unroll
    for (int p = 0; p < 4; ++p) {
        int idx = p * 256 + tid;
        int r = idx >> 4, c = (idx & 15) * 4;
        float4 v = *reinterpret_cast<const float4*>(&W[(size_t)(k0 + r) * N + n0 + c]);
        *reinterpret_cast<float4*>(&tile[r][c]) = v;
    }
    __syncthreads();
#pragma unroll
    for (int p = 0; p < 4; ++p) {
        int idx = p * 256 + tid;
        int nr = idx >> 4, kg = (idx & 15) * 4;
        u16 u[4];
#pragma unroll
        for (int j = 0; j < 4; ++j) u[j] = f2bfu(tile[kg + j][nr]);
        *reinterpret_cast<uint2*>(&Wt[(size_t)(n0 + nr) * K + k0 + kg]) =
            *reinterpret_cast<const uint2*>(u);
    }
}

// ---------------- GEMM: C[M,N] = A[M,K] @ Bt[N,K]^T + bias ----------------
template <int F32OUT>
__global__ __launch_bounds__(256) void gemm_bt(const u16* __restrict__ A,
                                               const u16* __restrict__ Bt,
                                               const float* __restrict__ bias,
                                               float* __restrict__ Cf,
                                               u16* __restrict__ Cb,
                                               int M, int N, int K) {
    __shared__ __align__(16) u16 As[128 * 32];
    __shared__ __align__(16) u16 Bs[128 * 32];
    const int tid = threadIdx.x;
    const int wid = tid >> 6, lane = tid & 63;
    const int lhi = lane >> 4, llo = lane & 15;
    const int m0 = blockIdx.y * 128, n0 = blockIdx.x * 128;
    const int wr = wid >> 1, wc = wid & 1;

    f32x4 acc[4][4];
#pragma unroll
    for (int i = 0; i < 4; ++i)
#pragma unroll
        for (int j = 0; j < 4; ++j) acc[i][j] = (f32x4){0.f, 0.f, 0.f, 0.f};

    for (int k0 = 0; k0 < K; k0 += 32) {
        __syncthreads();
#pragma unroll
        for (int p = 0; p < 2; ++p) {
            int idx = p * 256 + tid;
            int row = idx >> 2, kc = (idx & 3) * 8;
            gload_lds16(A + (size_t)(m0 + row) * K + k0 + kc,
                        As + (size_t)(p * 256 + wid * 64) * 8);
            gload_lds16(Bt + (size_t)(n0 + row) * K + k0 + kc,
                        Bs + (size_t)(p * 256 + wid * 64) * 8);
        }
        __syncthreads();
        bf16x8 af[4], bfr[4];
#pragma unroll
        for (int mt = 0; mt < 4; ++mt)
            af[mt] = ld_frag(&As[(wr * 64 + mt * 16 + llo) * 32 + lhi * 8]);
#pragma unroll
        for (int nt = 0; nt < 4; ++nt)
            bfr[nt] = ld_frag(&Bs[(wc * 64 + nt * 16 + llo) * 32 + lhi * 8]);
#pragma unroll
        for (int mt = 0; mt < 4; ++mt)
#pragma unroll
            for (int nt = 0; nt < 4; ++nt)
                acc[mt][nt] = __builtin_amdgcn_mfma_f32_16x16x32_bf16(
                    af[mt], bfr[nt], acc[mt][nt], 0, 0, 0);
    }

    const int row_base = m0 + wr * 64;
    const int col_base = n0 + wc * 64;
#pragma unroll
    for (int nt = 0; nt < 4; ++nt) {
        int col = col_base + nt * 16 + llo;
        float bv = bias[col];
#pragma unroll
        for (int mt = 0; mt < 4; ++mt) {
#pragma unroll
            for (int r = 0; r < 4; ++r) {
                int row = row_base + mt * 16 + lhi * 4 + r;
                float v = acc[mt][nt][r] + bv;
                if (F32OUT)
                    Cf[(size_t)row * N + col] = v;
                else
                    Cb[(size_t)row * N + col] = f2bfu(v);
            }
        }
    }
}

// ---------------- causal flash attention, swapped-operand 32x32 MFMA ----------------
// Block: 256 thr (4 waves), wave owns 32 q rows -> block = 128 q rows.
// Grid: 1024 = 16 q-chunks x 64 (b,h); qc balance permutation over residency classes.
// K LDS layout: 520-u16 chunks (8 rows x 64 + 8 pad) -> row-start banks spread
// (fixes stride-128B bank aliasing) while keeping gload_lds dest linear per wave.
__global__ __launch_bounds__(256, 3) void attn_kernel(const u16* __restrict__ qkv,
                                                      u16* __restrict__ o) {
    __shared__ __align__(16) u16 smem[17536];  // K: 2x4160 u16 @0, Vt: 2x4608 u16 @8320
    const int bid = blockIdx.x;
    const int qcmap[16] = {15, 14, 13, 12, 8, 9, 10, 11, 4, 5, 6, 7, 3, 2, 1, 0};
    const int qc = qcmap[bid >> 6];
    const int bh = bid & 63;
    const int b = bh >> 4, h = bh & 15;
    const int tid = threadIdx.x;
    const int wid = tid >> 6, lane = tid & 63;
    const int l31 = lane & 31, lh = lane >> 5;
    const u16* base = qkv + (size_t)b * SEQ_T * (3 * DM);
    const int qrow0 = qc * 128 + wid * 32;
    const int q_abs = qrow0 + l31;
    const int nkv = 2 * qc + 2;

    // Q B-fragments: lane l31 = q, k(d) = km*16 + lh*8 + e  (natural row read)
    bf16x8 qf[4];
    {
        const u16* qp = base + (size_t)q_abs * (3 * DM) + h * HD + lh * 8;
#pragma unroll
        for (int km = 0; km < 4; ++km) qf[km] = ld_frag(qp + km * 16);
    }

    f32x16 oac0, oac1;  // O^T accs: lane l31 = q, d via (reg,lh)
#pragma unroll
    for (int r = 0; r < 16; ++r) { oac0[r] = 0.f; oac1[r] = 0.f; }
    float m_run = -1e30f, l_run = 0.f;

    uint4 va, vb;
    const int vpr = tid >> 3, vm = tid & 7;

    auto stageK = [&](int kb, int bi) {
#pragma unroll
        for (int p = 0; p < 2; ++p) {
            int kv = p * 32 + wid * 8 + (lane >> 3);
            int cl = lane & 7;
            const u16* src = base + (size_t)(kb * 64 + kv) * (3 * DM) + DM + h * HD +
                             ((cl ^ (kv & 7)) * 8);
            // dest: chunk (p*4+wid) of 520 u16 (8 rows x 64 + 8 pad), linear per wave
            gload_lds16(src, smem + bi * 4160 + (p * 4 + wid) * 520);
        }
    };
    auto loadV = [&](int kb) {
        const u16* vp =
            base + (size_t)(kb * 64 + 2 * vpr) * (3 * DM) + 2 * DM + h * HD + vm * 8;
        va = *reinterpret_cast<const uint4*>(vp);
        vb = *reinterpret_cast<const uint4*>(vp + 3 * DM);
    };
    auto writeV = [&](int bi) {  // Vt[d][kv], rows 72 u16, chunk-XOR swizzled
        u16 ua[8], ub[8];
        *reinterpret_cast<uint4*>(ua) = va;
        *reinterpret_cast<uint4*>(ub) = vb;
        const int cb = vpr >> 2, off = 2 * (vpr & 3);
        const int sw = (2 * vm) & 7;  // (2*(d>>3))&7, d>>3 == vm
        u16* vt = smem + 8320 + bi * 4608;
#pragma unroll
        for (int j = 0; j < 8; ++j) {
            int d = vm * 8 + j;
            u32t val = (u32t)ua[j] | ((u32t)ub[j] << 16);
            *reinterpret_cast<u32t*>(vt + d * 72 + ((cb ^ sw) * 8) + off) = val;
        }
    };

    stageK(0, 0);
    loadV(0);
    writeV(0);
    __syncthreads();

    const int vsw = (2 * (l31 >> 3)) & 7;
    const int qmax = qrow0 + 31;
    const float SC2 = 0.18033688f;  // (1/sqrt(64)) * log2(e); softmax in base-2
    // K row r at (r>>3)*520 + (r&7)*64; s0 rows l31, s1 rows 32+l31
    const int krow0 = (l31 >> 3) * 520 + (l31 & 7) * 64;
    const int krow1 = (4 + (l31 >> 3)) * 520 + (l31 & 7) * 64;

    for (int kb = 0; kb < nkv; ++kb) {
        const int cur = kb & 1;
        const bool pre = (kb + 1 < nkv);
        if (pre) { stageK(kb + 1, cur ^ 1); loadV(kb + 1); }

        if (kb * 64 <= qmax) {
            // ---- S^T = K · Q^T ----
            f32x16 s0, s1;
#pragma unroll
            for (int r = 0; r < 16; ++r) { s0[r] = 0.f; s1[r] = 0.f; }
            const u16* kbase = smem + cur * 4160;
            __builtin_amdgcn_s_setprio(1);
#pragma unroll
            for (int km = 0; km < 4; ++km) {
                bf16x8 kf = ld_frag(kbase + krow0 + (((km * 2 + lh) ^ (l31 & 7)) * 8));
                s0 = __builtin_amdgcn_mfma_f32_32x32x16_bf16(kf, qf[km], s0, 0, 0, 0);
            }
#pragma unroll
            for (int km = 0; km < 4; ++km) {
                bf16x8 kf = ld_frag(kbase + krow1 + (((km * 2 + lh) ^ (l31 & 7)) * 8));
                s1 = __builtin_amdgcn_mfma_f32_32x32x16_bf16(kf, qf[km], s1, 0, 0, 0);
            }
            __builtin_amdgcn_s_setprio(0);

            // ---- scale + causal mask ----
            if (kb * 64 + 63 > qrow0) {
#pragma unroll
                for (int r = 0; r < 16; ++r) {
                    int ka = kb * 64 + (r & 3) + 8 * (r >> 2) + 4 * lh;
                    s0[r] = (ka > q_abs) ? -1e30f : s0[r] * SC2;
                    s1[r] = (ka + 32 > q_abs) ? -1e30f : s1[r] * SC2;
                }
            } else {
#pragma unroll
                for (int r = 0; r < 16; ++r) { s0[r] *= SC2; s1[r] *= SC2; }
            }

            // ---- online softmax with defer-max (kv register-local) ----
            float pm = s0[0];
#pragma unroll
            for (int r = 1; r < 16; ++r) pm = fmaxf(pm, s0[r]);
#pragma unroll
            for (int r = 0; r < 16; ++r) pm = fmaxf(pm, s1[r]);
            pm = fmaxf(pm, __shfl_xor(pm, 32));
            if (!__all(pm - m_run <= 8.f)) {
                const float mnew = fmaxf(m_run, pm);
                const float sc = exp2f(m_run - mnew);
                m_run = mnew;
                l_run *= sc;
#pragma unroll
                for (int r = 0; r < 16; ++r) { oac0[r] *= sc; oac1[r] *= sc; }
            }
            float sum = 0.f;
#pragma unroll
            for (int r = 0; r < 16; ++r) { float p = exp2f(s0[r] - m_run); s0[r] = p; sum += p; }
#pragma unroll
            for (int r = 0; r < 16; ++r) { float p = exp2f(s1[r] - m_run); s1[r] = p; sum += p; }
            sum += __shfl_xor(sum, 32);
            l_run += sum;

            // ---- P -> bf16 B-fragments: cvt_pk + permlane32_swap ----
            u32t pk0[8], pk1[8];
#pragma unroll
            for (int w = 0; w < 8; ++w) {
                float a0 = s0[2 * w], b0 = s0[2 * w + 1];
                float a1 = s1[2 * w], b1 = s1[2 * w + 1];
                asm("v_cvt_pk_bf16_f32 %0, %1, %2" : "=v"(pk0[w]) : "v"(a0), "v"(b0));
                asm("v_cvt_pk_bf16_f32 %0, %1, %2" : "=v"(pk1[w]) : "v"(a1), "v"(b1));
            }
            asm("v_permlane32_swap_b32 %0, %1" : "+v"(pk0[0]), "+v"(pk0[2]));
            asm("v_permlane32_swap_b32 %0, %1" : "+v"(pk0[1]), "+v"(pk0[3]));
            asm("v_permlane32_swap_b32 %0, %1" : "+v"(pk0[4]), "+v"(pk0[6]));
            asm("v_permlane32_swap_b32 %0, %1" : "+v"(pk0[5]), "+v"(pk0[7]));
            asm("v_permlane32_swap_b32 %0, %1" : "+v"(pk1[0]), "+v"(pk1[2]));
            asm("v_permlane32_swap_b32 %0, %1" : "+v"(pk1[1]), "+v"(pk1[3]));
            asm("v_permlane32_swap_b32 %0, %1" : "+v"(pk1[4]), "+v"(pk1[6]));
            asm("v_permlane32_swap_b32 %0, %1" : "+v"(pk1[5]), "+v"(pk1[7]));
            bf16x8 pf[4];
            {
                uint4 t0 = {pk0[0], pk0[1], pk0[2], pk0[3]};
                uint4 t1 = {pk0[4], pk0[5], pk0[6], pk0[7]};
                uint4 t2 = {pk1[0], pk1[1], pk1[2], pk1[3]};
                uint4 t3 = {pk1[4], pk1[5], pk1[6], pk1[7]};
                pf[0] = __builtin_bit_cast(bf16x8, t0);
                pf[1] = __builtin_bit_cast(bf16x8, t1);
                pf[2] = __builtin_bit_cast(bf16x8, t2);
                pf[3] = __builtin_bit_cast(bf16x8, t3);
            }

            // ---- O^T += V^T · P^T ----
            const u16* vbase = smem + 8320 + cur * 4608;
            __builtin_amdgcn_s_setprio(1);
#pragma unroll
            for (int km = 0; km < 4; ++km) {
                bf16x8 vf = ld_frag(vbase + l31 * 72 + (((km * 2 + lh) ^ vsw) * 8));
                oac0 = __builtin_amdgcn_mfma_f32_32x32x16_bf16(vf, pf[km], oac0, 0, 0, 0);
            }
#pragma unroll
            for (int km = 0; km < 4; ++km) {
                bf16x8 vf = ld_frag(vbase + (32 + l31) * 72 + (((km * 2 + lh) ^ vsw) * 8));
                oac1 = __builtin_amdgcn_mfma_f32_32x32x16_bf16(vf, pf[km], oac1, 0, 0, 0);
            }
            __builtin_amdgcn_s_setprio(0);
        }

        if (pre) writeV(cur ^ 1);
        __syncthreads();
    }

    // ---- epilogue: normalize, transpose O^T->O via LDS, coalesced store ----
    const float inv = 1.f / l_run;
    u16* osh = smem + wid * 2240;  // per-wave [32 q][70 u16]
#pragma unroll
    for (int r = 0; r < 16; ++r) {
        int dl = (r & 3) + 8 * (r >> 2) + 4 * lh;
        osh[l31 * 70 + dl] = f2bfu(oac0[r] * inv);
        osh[l31 * 70 + 32 + dl] = f2bfu(oac1[r] * inv);
    }
    __syncthreads();
    {
        // lane (l31, lh) writes q = l31, d = lh*32 + 0..31  (full 64-d coverage)
        const u16* rs = osh + l31 * 70 + lh * 32;
        u16* op = o + (size_t)(b * SEQ_T + qrow0 + l31) * DM + h * HD + lh * 32;
        u32t w[16];
#pragma unroll
        for (int i = 0; i < 16; ++i) w[i] = *reinterpret_cast<const u32t*>(rs + i * 2);
#pragma unroll
        for (int i = 0; i < 4; ++i) {
            uint4 t = {w[4 * i], w[4 * i + 1], w[4 * i + 2], w[4 * i + 3]};
            *reinterpret_cast<uint4*>(op + 8 * i) = t;
        }
    }
}

extern "C" void kernel_launch(void* const* d_in, const int* in_sizes, int n_in,
                              void* d_out, int out_size, void* d_ws, size_t ws_size,
                              hipStream_t stream) {
    const float* x = (const float*)d_in[0];
    const float* Wqkv = (const float*)d_in[1];
    const float* bqkv = (const float*)d_in[2];
    const float* Wproj = (const float*)d_in[3];
    const float* bproj = (const float*)d_in[4];
    float* out = (float*)d_out;
    char* ws = (char*)d_ws;

    u16* xb   = (u16*)(ws);                         // 16,777,216 B
    u16* wtq  = (u16*)(ws + 16777216);              //  6,291,456 B
    u16* wtp  = (u16*)(ws + 23068672);              //  2,097,152 B
    u16* qkvb = (u16*)(ws + 25165824);              // 50,331,648 B
    u16* ob   = (u16*)(ws + 75497472);              // 16,777,216 B

    cvt_x_kernel<<<4096, 256, 0, stream>>>(x, xb);
    trans_w<<<dim3(3072 / 64, 1024 / 64), 256, 0, stream>>>(Wqkv, wtq, 1024, 3072);
    trans_w<<<dim3(1024 / 64, 1024 / 64), 256, 0, stream>>>(Wproj, wtp, 1024, 1024);

    gemm_bt<0><<<dim3(3072 / 128, 8192 / 128), 256, 0, stream>>>(
        xb, wtq, bqkv, nullptr, qkvb, 8192, 3072, 1024);

    attn_kernel<<<1024, 256, 0, stream>>>(qkvb, ob);

    gemm_bt<1><<<dim3(1024 / 128, 8192 / 128), 256, 0, stream>>>(
        ob, wtp, bproj, out, nullptr, 8192, 1024, 1024);
}